// Round 8
// baseline (1812.282 us; speedup 1.0000x reference)
//
#include <hip/hip_runtime.h>

#define NN 50000
#define NE 800000
#define NG 128
#define NK 800000          // NN*16 sort keys (node,cell)
#define NB2 3125           // NK/256, NE/256 (both exact)

typedef unsigned int uint;
typedef unsigned short ushort;
typedef __attribute__((ext_vector_type(8))) short short8;
typedef __attribute__((ext_vector_type(4))) float f32x4;

__device__ __forceinline__ float bf2f(ushort u){ union{uint i; float f;} v; v.i=(uint)u<<16; return v.f; }
__device__ __forceinline__ ushort f2bf(float f){ union{float f; uint i;} v; v.f=f; return (ushort)((v.i + 0x7FFFu + ((v.i>>16)&1u))>>16); }

// ---------------- zero scratch re-initialized every call ----------------
__global__ void zero_k(int* hist2, float* pooled, int* gcnt){
    int i = blockIdx.x*blockDim.x + threadIdx.x;
    if (i < NK) hist2[i] = 0;
    if (i < NG*64) pooled[i] = 0.f;
    if (i < NG) gcnt[i] = 0;
}

// ---------------- (dst,cell) histogram ----------------
__global__ void hist_k(const int* __restrict__ ei, const float* __restrict__ pseudo, int* __restrict__ hist2){
    int e = blockIdx.x*blockDim.x + threadIdx.x;
    if (e >= NE) return;
    float2 ps = *(const float2*)(pseudo + 2*(size_t)e);
    int lx = min(max((int)floorf(ps.x*4.0f), 0), 3);
    int ly = min(max((int)floorf(ps.y*4.0f), 0), 3);
    atomicAdd(&hist2[ei[NE + e]*16 + ly*4 + lx], 1);
}

// ---------------- hierarchical exclusive scan over NK keys ----------------
__global__ __launch_bounds__(256) void scan1(const int* __restrict__ hist2, int* __restrict__ bsum){
    __shared__ int sm[256];
    int t = threadIdx.x, i = blockIdx.x*256 + t;
    sm[t] = (i < NK) ? hist2[i] : 0;
    __syncthreads();
    for (int o = 128; o > 0; o >>= 1){ if (t < o) sm[t] += sm[t+o]; __syncthreads(); }
    if (t == 0) bsum[blockIdx.x] = sm[0];
}
__global__ __launch_bounds__(1024) void scan2(const int* __restrict__ bsum, int* __restrict__ bpre){
    __shared__ int sm[1024];
    int t = threadIdx.x;
    const int CH = (NB2 + 1023)/1024;     // 4
    int base = t*CH, lim = min(base+CH, NB2);
    int s = 0;
    for (int i = base; i < lim; ++i) s += bsum[i];
    sm[t] = s; __syncthreads();
    int acc = s;
    for (int o = 1; o < 1024; o <<= 1){
        int u = (t >= o) ? sm[t-o] : 0; __syncthreads();
        acc += u; sm[t] = acc; __syncthreads();
    }
    int run = acc - s;
    for (int i = base; i < lim; ++i){ bpre[i] = run; run += bsum[i]; }
}
__global__ __launch_bounds__(256) void scan3(const int* __restrict__ hist2, const int* __restrict__ bpre,
                                             int* __restrict__ offs2k, int* __restrict__ cursor){
    __shared__ int sm[256];
    int t = threadIdx.x, b = blockIdx.x, i = b*256 + t;
    int v = (i < NK) ? hist2[i] : 0;
    sm[t] = v; __syncthreads();
    int acc = v;
    for (int o = 1; o < 256; o <<= 1){
        int u = (t >= o) ? sm[t-o] : 0; __syncthreads();
        acc += u; sm[t] = acc; __syncthreads();
    }
    int excl = acc - v + bpre[b];
    if (i < NK){ offs2k[i] = excl; cursor[i] = excl; }
    if (i == NK-1) offs2k[NK] = NE;
}
__global__ __launch_bounds__(256) void invc_k(const int* __restrict__ offs2k, float* __restrict__ invc){
    int n = blockIdx.x*blockDim.x + threadIdx.x;
    if (n < NN) invc[n] = 1.0f / (float)max(offs2k[n*16+16] - offs2k[n*16], 1);
}

// ---------------- counting sort by (dst,cell): payload[pos] = {src|lx|ly, fx, fy} ----------------
__global__ void scatter_k(const int* __restrict__ ei, const float* __restrict__ pseudo,
                          int* __restrict__ cursor, uint4* __restrict__ payload){
    int e = blockIdx.x*blockDim.x + threadIdx.x;
    if (e >= NE) return;
    float2 ps = *(const float2*)(pseudo + 2*(size_t)e);
    float px = ps.x * 4.0f, py = ps.y * 4.0f;
    int lx = min(max((int)floorf(px), 0), 3);
    int ly = min(max((int)floorf(py), 0), 3);
    float fx = px - (float)lx, fy = py - (float)ly;
    uint meta = (uint)ei[e] | ((uint)lx<<16) | ((uint)ly<<18);   // src < 65536
    int key = ei[NE + e]*16 + ly*4 + lx;
    int pos = atomicAdd(&cursor[key], 1);
    payload[pos] = make_uint4(meta, __float_as_uint(fx), __float_as_uint(fy), 0u);
}

// ---------------- pack [Wflat;root] into MFMA B-fragment layout, bf16 ----------------
// Bp[(kt*4+ct)*512 + lane*8 + j] = Bmat[kt*32 + (lane>>4)*8 + j][ct*16 + (lane&15)]
template<int IN>
__global__ void wprep_k(const float* __restrict__ W, const float* __restrict__ root, ushort* __restrict__ Bp){
    const int total = 26*IN*64;
    int tid = blockIdx.x*blockDim.x + threadIdx.x;
    if (tid >= total) return;
    int j    = tid & 7;
    int lane = (tid >> 3) & 63;
    int ctkt = tid >> 9;
    int ct   = ctkt & 3;
    int kt   = ctkt >> 2;
    int kk   = kt*32 + (lane>>4)*8 + j;
    int col  = ct*16 + (lane & 15);
    float v;
    if (kk < 25*IN){ int k = kk / IN; int i = kk % IN; v = W[((size_t)k*IN + i)*64 + col]; }
    else           { v = root[(size_t)(kk - 25*IN)*64 + col]; }
    Bp[tid] = f2bf(v);
}

// ---------------- layer 1: CSR reduce with tiny W1 in LDS (in=1, out=32) ----------------
__global__ __launch_bounds__(256) void reduce1_k(const float* __restrict__ x, const uint4* __restrict__ payload,
                                                 const int* __restrict__ offs2k, const float* __restrict__ invc,
                                                 const float* __restrict__ W1, const float* __restrict__ root1,
                                                 const float* __restrict__ b1, ushort* __restrict__ h1bf){
    __shared__ float w1s[25*32];
    for (int i = threadIdx.x; i < 25*32; i += 256) w1s[i] = W1[i];
    __syncthreads();
    int wid  = threadIdx.x >> 6;
    int lane = threadIdx.x & 63;
    int o    = lane & 31;
    int half = lane >> 5;
    int d    = blockIdx.x*4 + wid;
    int s = offs2k[d*16], e = offs2k[d*16+16];
    float acc = 0.f;
#define EDGE1(PL, XS) { uint meta = (PL).x; \
    int lx = (meta>>16)&3, ly = (meta>>18)&3; \
    float fx = __uint_as_float((PL).y), fy = __uint_as_float((PL).z); \
    float gx = 1.f - fx, gy = 1.f - fy; \
    int ka = ly*5 + lx + half; \
    float wa = half ? fx*gy : gx*gy; \
    float wb = half ? fx*fy : gx*fy; \
    acc += (wa*w1s[ka*32 + o] + wb*w1s[(ka+5)*32 + o]) * (XS); }
    int p = s;
    for (; p + 2 <= e; p += 2){
        uint4 A0 = payload[p], A1 = payload[p+1];
        float x0 = x[A0.x & 0xFFFF];
        float x1 = x[A1.x & 0xFFFF];
        EDGE1(A0, x0) EDGE1(A1, x1)
    }
    if (p < e){
        uint4 A0 = payload[p];
        float x0 = x[A0.x & 0xFFFF];
        EDGE1(A0, x0)
    }
#undef EDGE1
    acc += __shfl_xor(acc, 32);
    if (half == 0){
        float val = acc*invc[d] + x[d]*root1[o] + b1[o];
        val = val > 0.f ? val : expm1f(val);
        h1bf[(size_t)d*32 + o] = f2bf(val);
    }
}

// ---------------- fused layer with ds_add_f32 accumulation ----------------
// 256 threads = 4 waves. IN=64: 4 nodes/block (wave=node). IN=32: 8 nodes/block (half-wave=node).
// Edge phase: flat loop, unroll-4 (batched loads), returnless LDS float atomics -> no dep chain.
template<int IN, int MODE>
__global__ __launch_bounds__(256, 4) void fused_ds(
        const ushort* __restrict__ hin, const uint4* __restrict__ payload,
        const int* __restrict__ offs2k, const float* __restrict__ invc,
        const ushort* __restrict__ Bp, const float* __restrict__ bias,
        const int* __restrict__ batch, ushort* __restrict__ hout,
        float* __restrict__ pooled, int* __restrict__ gcnt)
{
    constexpr int NND = (IN == 64) ? 4 : 8;
    constexpr int KT  = 26*IN/32;                 // 52 / 26
    constexpr int SP  = 25*IN;                    // f32 accumulation stride
    constexpr int SW  = (IN == 64) ? 1688 : 856;  // ushort stride: %8==0 (b128), word%32==12 (bank spread)
    __shared__ __align__(16) float Sf[NND*SP];
    __shared__ float invS[NND];
    __shared__ float outS[NND*64];
    ushort* Sb = (ushort*)Sf;                     // bf16 A-tile overlays Sf after convert

    int tid = threadIdx.x, lane = tid & 63, w = tid >> 6;
    int d0 = blockIdx.x * NND;
    int node = (IN == 64) ? w : (w*2 + (lane >> 5));
    int li   = (IN == 64) ? lane : (lane & 31);
    int dd = d0 + node;

    for (int i = tid; i < NND*SP; i += 256) Sf[i] = 0.f;
    if (tid < NND) invS[tid] = invc[d0 + tid];
    __syncthreads();

    // ---- edge phase: fire-and-forget ds_add_f32 ----
    {
        int s = offs2k[dd*16], e = offs2k[dd*16 + 16];
        float* Sw = Sf + node*SP;
        const ushort* hl = hin + li;
#define EDS(PL, XS) { uint meta = (PL).x; \
        int lx = (meta>>16)&3, ly = (meta>>18)&3; \
        float fx = __uint_as_float((PL).y), fy = __uint_as_float((PL).z); \
        float gx = 1.f - fx, gy = 1.f - fy; \
        int b00 = (ly*5 + lx)*IN + li; \
        atomicAdd(&Sw[b00],      gx*gy*(XS)); \
        atomicAdd(&Sw[b00+IN],   fx*gy*(XS)); \
        atomicAdd(&Sw[b00+5*IN], gx*fy*(XS)); \
        atomicAdd(&Sw[b00+6*IN], fx*fy*(XS)); }
        int p = s;
        for (; p + 4 <= e; p += 4){
            uint4 p0 = payload[p], p1 = payload[p+1], p2 = payload[p+2], p3 = payload[p+3];
            float x0 = bf2f(hl[(size_t)(p0.x & 0xFFFF)*IN]);
            float x1 = bf2f(hl[(size_t)(p1.x & 0xFFFF)*IN]);
            float x2 = bf2f(hl[(size_t)(p2.x & 0xFFFF)*IN]);
            float x3 = bf2f(hl[(size_t)(p3.x & 0xFFFF)*IN]);
            EDS(p0, x0) EDS(p1, x1) EDS(p2, x2) EDS(p3, x3)
        }
        for (; p < e; ++p){
            uint4 p0 = payload[p];
            float x0 = bf2f(hl[(size_t)(p0.x & 0xFFFF)*IN]);
            EDS(p0, x0)
        }
#undef EDS
    }
    __syncthreads();

    // ---- convert to bf16 A-tile (reg-staged overlay), float2-vectorized, static 13 iters ----
    {
        float2 vals[13];
        #pragma unroll
        for (int k = 0; k < 13; ++k){
            int i2 = tid + k*256;                  // < NND*13*IN == 3328
            int n = i2 / (13*IN), c = (i2 - n*(13*IN))*2;
            if (c < 25*IN){
                float2 sv = *(const float2*)(Sf + n*SP + c);
                float ic = invS[n];
                vals[k] = make_float2(sv.x*ic, sv.y*ic);
            } else {
                uint hv = *(const uint*)(hin + (size_t)(d0+n)*IN + (c - 25*IN));
                vals[k] = make_float2(bf2f((ushort)hv), bf2f((ushort)(hv>>16)));
            }
        }
        __syncthreads();
        #pragma unroll
        for (int k = 0; k < 13; ++k){
            int i2 = tid + k*256;
            int n = i2 / (13*IN), c = (i2 - n*(13*IN))*2;
            uint pk = ((uint)f2bf(vals[k].y) << 16) | (uint)f2bf(vals[k].x);
            *(uint*)(Sb + n*SW + c) = pk;
        }
    }
    __syncthreads();

    // ---- GEMM: wave w = column-tile, full K ----
    {
        int ct = w, row = lane & 15;
        int nodeg = row & (NND-1);
        int cg = (lane >> 4)*8;
        f32x4 a4 = {0.f,0.f,0.f,0.f};
        const ushort* ab = Sb + nodeg*SW + cg;
        const ushort* bb = Bp + ct*512 + (size_t)lane*8;
        #pragma unroll
        for (int kt = 0; kt < KT; ++kt){
            short8 a = *(const short8*)(ab + kt*32);
            short8 b = *(const short8*)(bb + (size_t)kt*2048);
            a4 = __builtin_amdgcn_mfma_f32_16x16x32_bf16(a, b, a4, 0, 0, 0);
        }
        int col = ct*16 + (lane & 15);
        float bs = bias[col];
        int r0 = (lane >> 4)*4;
        #pragma unroll
        for (int j = 0; j < 4; ++j){
            int rr = r0 + j;
            if (rr < NND){
                float v = a4[j] + bs;
                v = v > 0.f ? v : expm1f(v);
                if (MODE == 0) ((ushort*)outS)[rr*64 + col] = f2bf(v);
                else           outS[rr*64 + col] = v;
            }
        }
    }
    __syncthreads();

    // ---- output ----
    if (MODE == 0){
        uint* dst = (uint*)(hout + (size_t)d0*64);
        const uint* srcp = (const uint*)outS;
        for (int i = tid; i < NND*32; i += 256) dst[i] = srcp[i];
    } else {
        if (w == 0){
            int c = lane;
            float run = 0.f; int gprev = batch[d0];
            for (int r = 0; r < NND; ++r){
                int g = batch[d0 + r];
                if (g != gprev){ atomicAdd(&pooled[gprev*64 + c], run); run = 0.f; gprev = g; }
                run += outS[r*64 + c];
            }
            atomicAdd(&pooled[gprev*64 + c], run);
        } else if (w == 1 && lane == 0){
            int cnt = 0; int gprev = batch[d0];
            for (int r = 0; r < NND; ++r){
                int g = batch[d0 + r];
                if (g != gprev){ atomicAdd(&gcnt[gprev], cnt); cnt = 0; gprev = g; }
                cnt++;
            }
            atomicAdd(&gcnt[gprev], cnt);
        }
    }
}

// ---------------- head: graph mean-pool -> fc -> log_softmax ----------------
__global__ __launch_bounds__(128) void head_k(const float* __restrict__ pooled, const int* __restrict__ gcnt,
                                              const float* __restrict__ fcw, const float* __restrict__ fcb,
                                              float* __restrict__ out){
    int g = threadIdx.x;
    if (g >= NG) return;
    float inv = 1.0f / fmaxf((float)gcnt[g], 1.0f);
    float logits[10];
    #pragma unroll
    for (int c = 0; c < 10; ++c) logits[c] = fcb[c];
    for (int o = 0; o < 64; ++o){
        float m = pooled[g*64 + o] * inv;
        #pragma unroll
        for (int c = 0; c < 10; ++c) logits[c] += m * fcw[o*10 + c];
    }
    float mx = logits[0];
    #pragma unroll
    for (int c = 1; c < 10; ++c) mx = fmaxf(mx, logits[c]);
    float ssum = 0.f;
    #pragma unroll
    for (int c = 0; c < 10; ++c) ssum += expf(logits[c] - mx);
    float lse = logf(ssum) + mx;
    #pragma unroll
    for (int c = 0; c < 10; ++c) out[g*10 + c] = logits[c] - lse;
}

extern "C" void kernel_launch(void* const* d_in, const int* in_sizes, int n_in,
                              void* d_out, int out_size, void* d_ws, size_t ws_size,
                              hipStream_t stream) {
    const float* x      = (const float*)d_in[0];
    const float* pseudo = (const float*)d_in[2];
    const int*   ei     = (const int*)  d_in[3];
    const int*   batch  = (const int*)  d_in[4];
    const float* W1     = (const float*)d_in[5];
    const float* root1  = (const float*)d_in[6];
    const float* b1     = (const float*)d_in[7];
    const float* W2     = (const float*)d_in[8];
    const float* root2  = (const float*)d_in[9];
    const float* b2     = (const float*)d_in[10];
    const float* W3     = (const float*)d_in[11];
    const float* root3  = (const float*)d_in[12];
    const float* b3     = (const float*)d_in[13];
    const float* fcw    = (const float*)d_in[14];
    const float* fcb    = (const float*)d_in[15];
    float* out = (float*)d_out;

    char* ws = (char*)d_ws;
    size_t off = 0;
    auto alloc = [&](size_t bytes)->char*{ char* p = ws + off; off += (bytes + 255) / 256 * 256; return p; };
    uint4*  payload= (uint4*) alloc((size_t)NE*16);
    ushort* h1bf   = (ushort*)alloc((size_t)NN*32*2);
    ushort* h2bf   = (ushort*)alloc((size_t)NN*64*2);
    int*    hist2  = (int*)   alloc((size_t)NK*4);
    int*    offs2k = (int*)   alloc((size_t)(NK+1)*4);
    int*    cursor = (int*)   alloc((size_t)NK*4);
    float*  invc   = (float*) alloc((size_t)NN*4);
    int*    bsum   = (int*)   alloc((size_t)NB2*4);
    int*    bpre   = (int*)   alloc((size_t)NB2*4);
    ushort* Bp2    = (ushort*)alloc((size_t)26*2048*2);
    ushort* Bp3    = (ushort*)alloc((size_t)52*2048*2);
    float*  pooled = (float*) alloc((size_t)NG*64*4);
    int*    gcnt   = (int*)   alloc((size_t)NG*4);
    (void)ws_size; (void)in_sizes; (void)n_in; (void)out_size;

    zero_k   <<<NB2, 256, 0, stream>>>(hist2, pooled, gcnt);
    hist_k   <<<NB2, 256, 0, stream>>>(ei, pseudo, hist2);
    scan1    <<<NB2, 256, 0, stream>>>(hist2, bsum);
    scan2    <<<1, 1024, 0, stream>>>(bsum, bpre);
    scan3    <<<NB2, 256, 0, stream>>>(hist2, bpre, offs2k, cursor);
    invc_k   <<<(NN+255)/256, 256, 0, stream>>>(offs2k, invc);
    scatter_k<<<NB2, 256, 0, stream>>>(ei, pseudo, cursor, payload);
    wprep_k<32><<<(26*32*64 + 255)/256, 256, 0, stream>>>(W2, root2, Bp2);
    wprep_k<64><<<(26*64*64 + 255)/256, 256, 0, stream>>>(W3, root3, Bp3);
    reduce1_k<<<NN/4, 256, 0, stream>>>(x, payload, offs2k, invc, W1, root1, b1, h1bf);
    fused_ds<32,0><<<NN/8, 256, 0, stream>>>(h1bf, payload, offs2k, invc, Bp2, b2, batch, h2bf, pooled, gcnt);
    fused_ds<64,1><<<NN/4, 256, 0, stream>>>(h2bf, payload, offs2k, invc, Bp3, b3, batch, h2bf, pooled, gcnt);
    head_k   <<<1, 128, 0, stream>>>(pooled, gcnt, fcw, fcb, out);
}

// Round 9
// 370.913 us; speedup vs baseline: 4.8860x; 4.8860x over previous
//
#include <hip/hip_runtime.h>

#define NN 50000
#define NE 800000
#define NG 128
#define NB_SCAN 196        // ceil(NN/256)
#define PADCAP 2350000     // NE + 31*NN worst-case padded slots

typedef unsigned int uint;
typedef unsigned short ushort;
typedef __attribute__((ext_vector_type(8))) short short8;
typedef __attribute__((ext_vector_type(4))) float f32x4;

__device__ __forceinline__ float bf2f(ushort u){ union{uint i; float f;} v; v.i=(uint)u<<16; return v.f; }
__device__ __forceinline__ ushort f2bf(float f){ union{float f; uint i;} v; v.f=f; return (ushort)((v.i + 0x7FFFu + ((v.i>>16)&1u))>>16); }

// ---------------- zero scratch re-initialized every call ----------------
__global__ void zero_k(int* hist, float* pooled, int* gcnt){
    int i = blockIdx.x*blockDim.x + threadIdx.x;
    if (i < NN) hist[i] = 0;
    if (i < NG*64) pooled[i] = 0.f;
    if (i < NG) gcnt[i] = 0;
}
__global__ void zero_pay(uint4* payload){
    int i = blockIdx.x*blockDim.x + threadIdx.x;
    if (i < PADCAP) payload[i] = make_uint4(0u,0u,0u,0u);
}

// ---------------- dst histogram ----------------
__global__ void hist_k(const int* __restrict__ ei, int* __restrict__ hist){
    int e = blockIdx.x*blockDim.x + threadIdx.x;
    if (e < NE) atomicAdd(&hist[ei[NE + e]], 1);
}

// ---------------- hierarchical exclusive scan of PADDED counts ----------------
__global__ __launch_bounds__(256) void scan1p(const int* __restrict__ hist, int* __restrict__ bsum){
    __shared__ int sm[256];
    int t = threadIdx.x, i = blockIdx.x*256 + t;
    int h = (i < NN) ? hist[i] : 0;
    sm[t] = ((h + 31) >> 5) << 5;
    __syncthreads();
    for (int o = 128; o > 0; o >>= 1){ if (t < o) sm[t] += sm[t+o]; __syncthreads(); }
    if (t == 0) bsum[blockIdx.x] = sm[0];
}
__global__ __launch_bounds__(256) void scan2p(const int* __restrict__ bsum, int* __restrict__ bpre){
    __shared__ int sm[256];
    int t = threadIdx.x;
    int v = (t < NB_SCAN) ? bsum[t] : 0;
    sm[t] = v; __syncthreads();
    int acc = v;
    for (int o = 1; o < 256; o <<= 1){
        int u = (t >= o) ? sm[t-o] : 0; __syncthreads();
        acc += u; sm[t] = acc; __syncthreads();
    }
    if (t < NB_SCAN) bpre[t] = acc - v;
}
__global__ __launch_bounds__(256) void scan3p(const int* __restrict__ hist, const int* __restrict__ bpre,
                                              int* __restrict__ offsP, int* __restrict__ cursor,
                                              float* __restrict__ invc){
    __shared__ int sm[256];
    int t = threadIdx.x, b = blockIdx.x, i = b*256 + t;
    int h = (i < NN) ? hist[i] : 0;
    int pc = ((h + 31) >> 5) << 5;
    sm[t] = pc; __syncthreads();
    int acc = pc;
    for (int o = 1; o < 256; o <<= 1){
        int u = (t >= o) ? sm[t-o] : 0; __syncthreads();
        acc += u; sm[t] = acc; __syncthreads();
    }
    int excl = acc - pc + bpre[b];
    if (i < NN){ offsP[i] = excl; cursor[i] = excl; invc[i] = 1.0f/(float)max(h,1); }
    if (i == NN-1) offsP[NN] = excl + pc;
}

// ---------------- counting sort into padded segments: payload = {meta, fx, fy, 1-fy} ----------------
__global__ void scatter_k(const int* __restrict__ ei, const float* __restrict__ pseudo,
                          int* __restrict__ cursor, uint4* __restrict__ payload){
    int e = blockIdx.x*blockDim.x + threadIdx.x;
    if (e >= NE) return;
    float2 ps = *(const float2*)(pseudo + 2*(size_t)e);
    float px = ps.x * 4.0f, py = ps.y * 4.0f;
    int lx = min(max((int)floorf(px), 0), 3);
    int ly = min(max((int)floorf(py), 0), 3);
    float fx = px - (float)lx, fy = py - (float)ly;
    uint meta = (uint)ei[e] | ((uint)lx<<16) | ((uint)ly<<18);   // src < 65536
    int pos = atomicAdd(&cursor[ei[NE + e]], 1);
    payload[pos] = make_uint4(meta, __float_as_uint(fx), __float_as_uint(fy), __float_as_uint(1.0f - fy));
}

// ---------------- pack [Wflat;root] into MFMA B-fragment layout, bf16 ----------------
// Bp[(kt*4+ct)*512 + lane*8 + j] = Bmat[kt*32 + (lane>>4)*8 + j][ct*16 + (lane&15)]
template<int IN>
__global__ void wprep_k(const float* __restrict__ W, const float* __restrict__ root, ushort* __restrict__ Bp){
    const int total = 26*IN*64;
    int tid = blockIdx.x*blockDim.x + threadIdx.x;
    if (tid >= total) return;
    int j    = tid & 7;
    int lane = (tid >> 3) & 63;
    int ctkt = tid >> 9;
    int ct   = ctkt & 3;
    int kt   = ctkt >> 2;
    int kk   = kt*32 + (lane>>4)*8 + j;
    int col  = ct*16 + (lane & 15);
    float v;
    if (kk < 25*IN){ int k = kk / IN; int i = kk % IN; v = W[((size_t)k*IN + i)*64 + col]; }
    else           { v = root[(size_t)(kk - 25*IN)*64 + col]; }
    Bp[tid] = f2bf(v);
}

// ---------------- layer 1: CSR reduce with tiny W1 in LDS (in=1, out=32) ----------------
__global__ __launch_bounds__(256) void reduce1_k(const float* __restrict__ x, const uint4* __restrict__ payload,
                                                 const int* __restrict__ offsP, const int* __restrict__ hist,
                                                 const float* __restrict__ invc,
                                                 const float* __restrict__ W1, const float* __restrict__ root1,
                                                 const float* __restrict__ b1, ushort* __restrict__ h1bf){
    __shared__ float w1s[25*32];
    for (int i = threadIdx.x; i < 25*32; i += 256) w1s[i] = W1[i];
    __syncthreads();
    int wid  = threadIdx.x >> 6;
    int lane = threadIdx.x & 63;
    int o    = lane & 31;
    int half = lane >> 5;
    int d    = blockIdx.x*4 + wid;
    int s = offsP[d], e = s + hist[d];
    float acc = 0.f;
#define EDGE1(PL, XS) { uint meta = (PL).x; \
    int lx = (meta>>16)&3, ly = (meta>>18)&3; \
    float fx = __uint_as_float((PL).y), fyv = __uint_as_float((PL).z), gyv = __uint_as_float((PL).w); \
    float gx = 1.f - fx; \
    int ka = ly*5 + lx + half; \
    float wa = half ? fx*gyv : gx*gyv; \
    float wb = half ? fx*fyv : gx*fyv; \
    acc += (wa*w1s[ka*32 + o] + wb*w1s[(ka+5)*32 + o]) * (XS); }
    int p = s;
    for (; p + 2 <= e; p += 2){
        uint4 A0 = payload[p], A1 = payload[p+1];
        float x0 = x[A0.x & 0xFFFF];
        float x1 = x[A1.x & 0xFFFF];
        EDGE1(A0, x0) EDGE1(A1, x1)
    }
    if (p < e){
        uint4 A0 = payload[p];
        float x0 = x[A0.x & 0xFFFF];
        EDGE1(A0, x0)
    }
#undef EDGE1
    acc += __shfl_xor(acc, 32);
    if (half == 0){
        float val = acc*invc[d] + x[d]*root1[o] + b1[o];
        val = val > 0.f ? val : expm1f(val);
        h1bf[(size_t)d*32 + o] = f2bf(val);
    }
}

// ---------------- fused layer: per-node MFMA edge-GEMM (S = C^T x H) + node-GEMM ----------------
// 512 threads = 8 waves. IN=32: 2 nodes/wave (16/block); IN=64: 1 node/wave (8/block).
// Edge segments padded to x32 with zero-coefficient slots. Coefficients split bf16 hi+lo (f32-grade).
template<int IN, int MODE>
__global__ __launch_bounds__(512) void fused_mf(
        const ushort* __restrict__ hin, const uint4* __restrict__ payload,
        const int* __restrict__ offsP, const float* __restrict__ invc,
        const ushort* __restrict__ Bp, const float* __restrict__ bias,
        const int* __restrict__ batch, ushort* __restrict__ hout,
        float* __restrict__ pooled, int* __restrict__ gcnt)
{
    constexpr int NPW = (IN == 64) ? 1 : 2;
    constexpr int NND = 8*NPW;
    constexpr int NCT = IN/16;
    constexpr int KT  = 26*IN/32, KH = KT/2;
    constexpr int SW  = 26*IN + 8;
    __shared__ __align__(16) ushort Sb[NND*SW];
    __shared__ __align__(16) uint4 estage[8][NPW*32];
    __shared__ float red[1024];
    __shared__ float outS[1024];

    int tid = threadIdx.x, lane = tid & 63, w = tid >> 6;
    int c15 = lane & 15, kg = lane >> 4;
    int d0 = blockIdx.x * NND;
    int i0 = c15 % 5, j0 = c15 / 5;          // spline (x,y) idx for M-tile0 row c15
    int r2 = 16 + c15;
    int i2v = r2 % 5, j2v = r2 / 5;          // M-tile1 row
    bool v2 = (r2 < 25);

    for (int nn = 0; nn < NPW; ++nn){
        int node = w*NPW + nn, d = d0 + node;
        int base = offsP[d];
        int steps = (offsP[d+1] - base) >> 5;
        f32x4 aS[2*NCT];
        #pragma unroll
        for (int q = 0; q < 2*NCT; ++q) aS[q] = (f32x4){0.f,0.f,0.f,0.f};

        for (int ks = 0; ks < steps; ++ks){
            int eb = base + ks*32;
            if (lane < 32) estage[w][nn*32 + lane] = payload[eb + lane];
            short8 ah0, al0, ah1, al1;
            int srcs[8];
            #pragma unroll
            for (int j = 0; j < 8; ++j){
                uint4 ed = estage[w][nn*32 + kg*8 + j];
                float fx = __uint_as_float(ed.y), fyv = __uint_as_float(ed.z), gyv = __uint_as_float(ed.w);
                int lx = (ed.x>>16)&3, ly = (ed.x>>18)&3;
                float gx = 1.f - fx;
                float wx0 = (i0==lx) ? gx : ((i0==lx+1) ? fx : 0.f);
                float wy0 = (j0==ly) ? gyv : ((j0==ly+1) ? fyv : 0.f);
                float w0 = wx0*wy0;
                ushort h0 = f2bf(w0); float l0 = w0 - bf2f(h0);
                ah0[j] = (short)h0; al0[j] = (short)f2bf(l0);
                float wx2 = (i2v==lx) ? gx : ((i2v==lx+1) ? fx : 0.f);
                float wy2 = (j2v==ly) ? gyv : ((j2v==ly+1) ? fyv : 0.f);
                float w1 = v2 ? wx2*wy2 : 0.f;
                ushort h1 = f2bf(w1); float l1 = w1 - bf2f(h1);
                ah1[j] = (short)h1; al1[j] = (short)f2bf(l1);
                srcs[j] = (int)(ed.x & 0xFFFF);
            }
            short8 bf[NCT];
            #pragma unroll
            for (int ct = 0; ct < NCT; ++ct)
                #pragma unroll
                for (int j = 0; j < 8; ++j)
                    bf[ct][j] = (short)hin[(size_t)srcs[j]*IN + ct*16 + c15];
            #pragma unroll
            for (int ct = 0; ct < NCT; ++ct){
                aS[ct]     = __builtin_amdgcn_mfma_f32_16x16x32_bf16(ah0, bf[ct], aS[ct],     0,0,0);
                aS[ct]     = __builtin_amdgcn_mfma_f32_16x16x32_bf16(al0, bf[ct], aS[ct],     0,0,0);
                aS[NCT+ct] = __builtin_amdgcn_mfma_f32_16x16x32_bf16(ah1, bf[ct], aS[NCT+ct], 0,0,0);
                aS[NCT+ct] = __builtin_amdgcn_mfma_f32_16x16x32_bf16(al1, bf[ct], aS[NCT+ct], 0,0,0);
            }
        }
        // deposit S rows (spline r, feature c) as big-GEMM A-tile, + h row (root cols)
        float ic = invc[d];
        #pragma unroll
        for (int mt = 0; mt < 2; ++mt)
            #pragma unroll
            for (int ct = 0; ct < NCT; ++ct)
                #pragma unroll
                for (int q = 0; q < 4; ++q){
                    int r = mt*16 + kg*4 + q;
                    if (r < 25) Sb[node*SW + r*IN + ct*16 + c15] = f2bf(aS[mt*NCT+ct][q]*ic);
                }
        if (IN == 64) Sb[node*SW + 25*64 + lane] = hin[(size_t)d*64 + lane];
        else if (lane < 32) Sb[node*SW + 25*32 + lane] = hin[(size_t)d*32 + lane];
    }
    __syncthreads();

    // ---- node-GEMM: 8 waves = 4 col-tiles x 2 K-halves ----
    {
        int ct = w & 3, kh = w >> 2;
        int nodeg = c15 & (NND-1);
        int cg = kg*8;
        f32x4 a4 = {0.f,0.f,0.f,0.f};
        const ushort* ab = Sb + nodeg*SW + cg;
        const ushort* bb = Bp + ct*512 + (size_t)lane*8;
        #pragma unroll
        for (int k = 0; k < KH; ++k){
            int kt = kh*KH + k;
            short8 a = *(const short8*)(ab + kt*32);
            short8 b = *(const short8*)(bb + (size_t)kt*2048);
            a4 = __builtin_amdgcn_mfma_f32_16x16x32_bf16(a, b, a4, 0, 0, 0);
        }
        if (kh == 1){
            float* r = red + (ct*64 + lane)*4;
            r[0]=a4[0]; r[1]=a4[1]; r[2]=a4[2]; r[3]=a4[3];
        }
        __syncthreads();
        if (kh == 0){
            const float* r = red + (ct*64 + lane)*4;
            int col = ct*16 + c15;
            float bs = bias[col];
            #pragma unroll
            for (int j = 0; j < 4; ++j){
                int rr = kg*4 + j;
                if (rr < NND){
                    float v = a4[j] + r[j] + bs;
                    v = v > 0.f ? v : expm1f(v);
                    if (MODE == 0) ((ushort*)outS)[rr*64 + col] = f2bf(v);
                    else           outS[rr*64 + col] = v;
                }
            }
        }
    }
    __syncthreads();

    // ---- output ----
    if (MODE == 0){
        uint* dst = (uint*)(hout + (size_t)d0*64);
        const uint* srcp = (const uint*)outS;
        for (int i = tid; i < NND*32; i += 512) dst[i] = srcp[i];
    } else {
        if (w == 0){
            int c = lane;
            float run = 0.f; int gprev = batch[d0];
            for (int r = 0; r < NND; ++r){
                int g = batch[d0 + r];
                if (g != gprev){ atomicAdd(&pooled[gprev*64 + c], run); run = 0.f; gprev = g; }
                run += outS[r*64 + c];
            }
            atomicAdd(&pooled[gprev*64 + c], run);
        } else if (w == 1 && lane == 0){
            int cnt = 0; int gprev = batch[d0];
            for (int r = 0; r < NND; ++r){
                int g = batch[d0 + r];
                if (g != gprev){ atomicAdd(&gcnt[gprev], cnt); cnt = 0; gprev = g; }
                cnt++;
            }
            atomicAdd(&gcnt[gprev], cnt);
        }
    }
}

// ---------------- head: graph mean-pool -> fc -> log_softmax ----------------
__global__ __launch_bounds__(128) void head_k(const float* __restrict__ pooled, const int* __restrict__ gcnt,
                                              const float* __restrict__ fcw, const float* __restrict__ fcb,
                                              float* __restrict__ out){
    int g = threadIdx.x;
    if (g >= NG) return;
    float inv = 1.0f / fmaxf((float)gcnt[g], 1.0f);
    float logits[10];
    #pragma unroll
    for (int c = 0; c < 10; ++c) logits[c] = fcb[c];
    for (int o = 0; o < 64; ++o){
        float m = pooled[g*64 + o] * inv;
        #pragma unroll
        for (int c = 0; c < 10; ++c) logits[c] += m * fcw[o*10 + c];
    }
    float mx = logits[0];
    #pragma unroll
    for (int c = 1; c < 10; ++c) mx = fmaxf(mx, logits[c]);
    float ssum = 0.f;
    #pragma unroll
    for (int c = 0; c < 10; ++c) ssum += expf(logits[c] - mx);
    float lse = logf(ssum) + mx;
    #pragma unroll
    for (int c = 0; c < 10; ++c) out[g*10 + c] = logits[c] - lse;
}

extern "C" void kernel_launch(void* const* d_in, const int* in_sizes, int n_in,
                              void* d_out, int out_size, void* d_ws, size_t ws_size,
                              hipStream_t stream) {
    const float* x      = (const float*)d_in[0];
    const float* pseudo = (const float*)d_in[2];
    const int*   ei     = (const int*)  d_in[3];
    const int*   batch  = (const int*)  d_in[4];
    const float* W1     = (const float*)d_in[5];
    const float* root1  = (const float*)d_in[6];
    const float* b1     = (const float*)d_in[7];
    const float* W2     = (const float*)d_in[8];
    const float* root2  = (const float*)d_in[9];
    const float* b2     = (const float*)d_in[10];
    const float* W3     = (const float*)d_in[11];
    const float* root3  = (const float*)d_in[12];
    const float* b3     = (const float*)d_in[13];
    const float* fcw    = (const float*)d_in[14];
    const float* fcb    = (const float*)d_in[15];
    float* out = (float*)d_out;

    char* ws = (char*)d_ws;
    size_t off = 0;
    auto alloc = [&](size_t bytes)->char*{ char* p = ws + off; off += (bytes + 255) / 256 * 256; return p; };
    uint4*  payload= (uint4*) alloc((size_t)PADCAP*16);
    ushort* h1bf   = (ushort*)alloc((size_t)NN*32*2);
    ushort* h2bf   = (ushort*)alloc((size_t)NN*64*2);
    int*    hist   = (int*)   alloc((size_t)NN*4);
    int*    offsP  = (int*)   alloc((size_t)(NN+1)*4);
    int*    cursor = (int*)   alloc((size_t)NN*4);
    float*  invc   = (float*) alloc((size_t)NN*4);
    int*    bsum   = (int*)   alloc((size_t)NB_SCAN*4);
    int*    bpre   = (int*)   alloc((size_t)NB_SCAN*4);
    ushort* Bp2    = (ushort*)alloc((size_t)26*2048*2);
    ushort* Bp3    = (ushort*)alloc((size_t)52*2048*2);
    float*  pooled = (float*) alloc((size_t)NG*64*4);
    int*    gcnt   = (int*)   alloc((size_t)NG*4);
    (void)ws_size; (void)in_sizes; (void)n_in; (void)out_size;

    zero_k   <<<NB_SCAN, 256, 0, stream>>>(hist, pooled, gcnt);
    zero_pay <<<(PADCAP+255)/256, 256, 0, stream>>>(payload);
    hist_k   <<<(NE+255)/256, 256, 0, stream>>>(ei, hist);
    scan1p   <<<NB_SCAN, 256, 0, stream>>>(hist, bsum);
    scan2p   <<<1, 256, 0, stream>>>(bsum, bpre);
    scan3p   <<<NB_SCAN, 256, 0, stream>>>(hist, bpre, offsP, cursor, invc);
    scatter_k<<<(NE+255)/256, 256, 0, stream>>>(ei, pseudo, cursor, payload);
    wprep_k<32><<<(26*32*64 + 255)/256, 256, 0, stream>>>(W2, root2, Bp2);
    wprep_k<64><<<(26*64*64 + 255)/256, 256, 0, stream>>>(W3, root3, Bp3);
    reduce1_k<<<NN/4, 256, 0, stream>>>(x, payload, offsP, hist, invc, W1, root1, b1, h1bf);
    fused_mf<32,0><<<NN/16, 512, 0, stream>>>(h1bf, payload, offsP, invc, Bp2, b2, batch, h2bf, pooled, gcnt);
    fused_mf<64,1><<<NN/8,  512, 0, stream>>>(h2bf, payload, offsP, invc, Bp3, b3, batch, h2bf, pooled, gcnt);
    head_k   <<<1, 128, 0, stream>>>(pooled, gcnt, fcw, fcb, out);
}

// Round 10
// 365.015 us; speedup vs baseline: 4.9649x; 1.0162x over previous
//
#include <hip/hip_runtime.h>

#define NN 50000
#define NE 800000
#define NG 128
#define NB_SCAN 196        // ceil(NN/256)
#define PADCAP 1550000     // NE + 15*NN worst-case padded slots

typedef unsigned int uint;
typedef unsigned short ushort;
typedef __attribute__((ext_vector_type(8))) short short8;
typedef __attribute__((ext_vector_type(4))) float f32x4;
typedef __attribute__((ext_vector_type(16))) float f32x16;

__device__ __forceinline__ float bf2f(ushort u){ union{uint i; float f;} v; v.i=(uint)u<<16; return v.f; }
__device__ __forceinline__ ushort f2bf(float f){ union{float f; uint i;} v; v.f=f; return (ushort)((v.i + 0x7FFFu + ((v.i>>16)&1u))>>16); }

// ---------------- zero scratch re-initialized every call ----------------
__global__ void zero_k(int* hist, float* pooled, int* gcnt){
    int i = blockIdx.x*blockDim.x + threadIdx.x;
    if (i < NN) hist[i] = 0;
    if (i < NG*64) pooled[i] = 0.f;
    if (i < NG) gcnt[i] = 0;
}

// ---------------- dst histogram ----------------
__global__ void hist_k(const int* __restrict__ ei, int* __restrict__ hist){
    int e = blockIdx.x*blockDim.x + threadIdx.x;
    if (e < NE) atomicAdd(&hist[ei[NE + e]], 1);
}

// ---------------- hierarchical exclusive scan of counts padded to x16 ----------------
__global__ __launch_bounds__(256) void scan1p(const int* __restrict__ hist, int* __restrict__ bsum){
    __shared__ int sm[256];
    int t = threadIdx.x, i = blockIdx.x*256 + t;
    int h = (i < NN) ? hist[i] : 0;
    sm[t] = (h + 15) & ~15;
    __syncthreads();
    for (int o = 128; o > 0; o >>= 1){ if (t < o) sm[t] += sm[t+o]; __syncthreads(); }
    if (t == 0) bsum[blockIdx.x] = sm[0];
}
__global__ __launch_bounds__(256) void scan2p(const int* __restrict__ bsum, int* __restrict__ bpre){
    __shared__ int sm[256];
    int t = threadIdx.x;
    int v = (t < NB_SCAN) ? bsum[t] : 0;
    sm[t] = v; __syncthreads();
    int acc = v;
    for (int o = 1; o < 256; o <<= 1){
        int u = (t >= o) ? sm[t-o] : 0; __syncthreads();
        acc += u; sm[t] = acc; __syncthreads();
    }
    if (t < NB_SCAN) bpre[t] = acc - v;
}
__global__ __launch_bounds__(256) void scan3p(const int* __restrict__ hist, const int* __restrict__ bpre,
                                              int* __restrict__ offsP, int* __restrict__ cursor,
                                              float* __restrict__ invc){
    __shared__ int sm[256];
    int t = threadIdx.x, b = blockIdx.x, i = b*256 + t;
    int h = (i < NN) ? hist[i] : 0;
    int pc = (h + 15) & ~15;
    sm[t] = pc; __syncthreads();
    int acc = pc;
    for (int o = 1; o < 256; o <<= 1){
        int u = (t >= o) ? sm[t-o] : 0; __syncthreads();
        acc += u; sm[t] = acc; __syncthreads();
    }
    int excl = acc - pc + bpre[b];
    if (i < NN){ offsP[i] = excl; cursor[i] = excl; invc[i] = 1.0f/(float)max(h,1); }
    if (i == NN-1) offsP[NN] = excl + pc;
}

// ---------------- fill pad slots with zero-weight entries ----------------
__global__ void padfill(const int* __restrict__ hist, const int* __restrict__ offsP,
                        uint4* __restrict__ payload2){
    int t = blockIdx.x*blockDim.x + threadIdx.x;
    if (t >= NN*16) return;
    int d = t >> 4, k = t & 15;
    int h = hist[d];
    int padded = (h + 15) & ~15;
    int slot = h + k;
    if (slot < padded){
        size_t idx = (size_t)(offsP[d] + slot)*2;
        payload2[idx]   = make_uint4(0u,0u,0u,0u);
        payload2[idx+1] = make_uint4(0u,0u,0u,0u);
    }
}

// ---------------- counting sort: precompute packed bf16 hi/lo corner weights ----------------
// payload2[pos*2]   = {meta, hi01(w00|w10), hi23(w01|w11), lo01}
// payload2[pos*2+1] = {lo23, 0, 0, 0}
__global__ void scatter_k(const int* __restrict__ ei, const float* __restrict__ pseudo,
                          int* __restrict__ cursor, uint4* __restrict__ payload2){
    int e = blockIdx.x*blockDim.x + threadIdx.x;
    if (e >= NE) return;
    float2 ps = *(const float2*)(pseudo + 2*(size_t)e);
    float px = ps.x * 4.0f, py = ps.y * 4.0f;
    int lx = min(max((int)floorf(px), 0), 3);
    int ly = min(max((int)floorf(py), 0), 3);
    float fx = px - (float)lx, fy = py - (float)ly;
    float gx = 1.f - fx, gy = 1.f - fy;
    float w00 = gx*gy, w10 = fx*gy, w01 = gx*fy, w11 = fx*fy;
    ushort h00 = f2bf(w00), h10 = f2bf(w10), h01 = f2bf(w01), h11 = f2bf(w11);
    ushort L00 = f2bf(w00 - bf2f(h00)), L10 = f2bf(w10 - bf2f(h10));
    ushort L01 = f2bf(w01 - bf2f(h01)), L11 = f2bf(w11 - bf2f(h11));
    uint meta = (uint)ei[e] | ((uint)lx<<16) | ((uint)ly<<18);   // src < 65536
    int pos = atomicAdd(&cursor[ei[NE + e]], 1);
    payload2[(size_t)pos*2]   = make_uint4(meta, (uint)h00 | ((uint)h10<<16),
                                                 (uint)h01 | ((uint)h11<<16),
                                                 (uint)L00 | ((uint)L10<<16));
    payload2[(size_t)pos*2+1] = make_uint4((uint)L01 | ((uint)L11<<16), 0u, 0u, 0u);
}

// ---------------- pack [Wflat;root] into MFMA B-fragment layout, bf16 ----------------
// Bp[(kt*4+ct)*512 + lane*8 + j] = Bmat[kt*32 + (lane>>4)*8 + j][ct*16 + (lane&15)]
template<int IN>
__global__ void wprep_k(const float* __restrict__ W, const float* __restrict__ root, ushort* __restrict__ Bp){
    const int total = 26*IN*64;
    int tid = blockIdx.x*blockDim.x + threadIdx.x;
    if (tid >= total) return;
    int j    = tid & 7;
    int lane = (tid >> 3) & 63;
    int ctkt = tid >> 9;
    int ct   = ctkt & 3;
    int kt   = ctkt >> 2;
    int kk   = kt*32 + (lane>>4)*8 + j;
    int col  = ct*16 + (lane & 15);
    float v;
    if (kk < 25*IN){ int k = kk / IN; int i = kk % IN; v = W[((size_t)k*IN + i)*64 + col]; }
    else           { v = root[(size_t)(kk - 25*IN)*64 + col]; }
    Bp[tid] = f2bf(v);
}

// ---------------- layer 1: CSR reduce with tiny W1 in LDS (in=1, out=32) ----------------
__global__ __launch_bounds__(256) void reduce1_k(const float* __restrict__ x, const uint4* __restrict__ payload2,
                                                 const int* __restrict__ offsP, const int* __restrict__ hist,
                                                 const float* __restrict__ invc,
                                                 const float* __restrict__ W1, const float* __restrict__ root1,
                                                 const float* __restrict__ b1, ushort* __restrict__ h1bf){
    __shared__ float w1s[25*32];
    for (int i = threadIdx.x; i < 25*32; i += 256) w1s[i] = W1[i];
    __syncthreads();
    int wid  = threadIdx.x >> 6;
    int lane = threadIdx.x & 63;
    int o    = lane & 31;
    int half = lane >> 5;
    int d    = blockIdx.x*4 + wid;
    int s = offsP[d], e = s + hist[d];
    float acc = 0.f;
    for (int p = s; p < e; ++p){
        uint4 q0 = payload2[(size_t)p*2];
        uint lo23 = payload2[(size_t)p*2+1].x;
        uint meta = q0.x;
        int lx = (meta>>16)&3, ly = (meta>>18)&3;
        float wa, wb;
        if (half == 0){ wa = bf2f((ushort)q0.y) + bf2f((ushort)q0.w);
                        wb = bf2f((ushort)q0.z) + bf2f((ushort)lo23); }
        else          { wa = bf2f((ushort)(q0.y>>16)) + bf2f((ushort)(q0.w>>16));
                        wb = bf2f((ushort)(q0.z>>16)) + bf2f((ushort)(lo23>>16)); }
        float xs = x[meta & 0xFFFF];
        int ka = ly*5 + lx + half;
        acc += (wa*w1s[ka*32 + o] + wb*w1s[(ka+5)*32 + o]) * xs;
    }
    acc += __shfl_xor(acc, 32);
    if (half == 0){
        float val = acc*invc[d] + x[d]*root1[o] + b1[o];
        val = val > 0.f ? val : expm1f(val);
        h1bf[(size_t)d*32 + o] = f2bf(val);
    }
}

// ---------------- fused layer: 32x32x16 edge-GEMM (S = C^T x H) + 16x16x32 node-GEMM ----------------
// 512 threads = 8 waves = 8 nodes/block for both layers. K-step = 16 edges (padded).
// Lane owns ONE spline row (lane&31); coefficients selected from packed bf16 hi/lo in payload.
template<int IN, int MODE>
__global__ __launch_bounds__(512) void fused_mf2(
        const ushort* __restrict__ hin, const uint4* __restrict__ payload2,
        const int* __restrict__ offsP, const float* __restrict__ invc,
        const ushort* __restrict__ Bp, const float* __restrict__ bias,
        const int* __restrict__ batch, ushort* __restrict__ hout,
        float* __restrict__ pooled, int* __restrict__ gcnt)
{
    constexpr int NCT = IN/32;            // feature col-tiles of 32
    constexpr int KT  = 26*IN/32, KH = KT/2;
    constexpr int SW  = 26*IN + 8;
    __shared__ __align__(16) ushort Sb[8*SW];
    __shared__ __align__(16) uint4 estage[8][32];
    __shared__ float red[1024];
    __shared__ float outS[512];

    const int tid = threadIdx.x, lane = tid & 63, w = tid >> 6;
    const int ln31 = lane & 31, kg2 = lane >> 5;
    const int d0 = blockIdx.x * 8;
    const int d  = d0 + w;
    const int i0 = ln31 % 5, j0 = ln31 / 5;
    const bool rv = (ln31 < 25);

    int base  = offsP[d];
    int steps = (offsP[d+1] - base) >> 4;

    f32x16 accH[NCT];
    #pragma unroll
    for (int ct = 0; ct < NCT; ++ct)
        #pragma unroll
        for (int q = 0; q < 16; ++q) accH[ct][q] = 0.f;

    for (int ks = 0; ks < steps; ++ks){
        if (lane < 32) estage[w][lane] = payload2[(size_t)(base + ks*16)*2 + lane];
        short8 ah, al;
        uint srcs[8];
        #pragma unroll
        for (int j = 0; j < 8; ++j){
            int es = kg2*8 + j;                 // edge slot (= K index)
            uint4 q0  = estage[w][es*2];
            uint lo23 = estage[w][es*2+1].x;
            uint meta = q0.x;
            int lx = (meta>>16)&3, ly = (meta>>18)&3;
            int dx = i0 - lx, dy = j0 - ly;
            bool ok = rv && ((uint)dx < 2u) && ((uint)dy < 2u);
            uint hiw = (dy == 1) ? q0.z : q0.y;
            uint low = (dy == 1) ? lo23 : q0.w;
            int sh = (dx & 1) << 4;
            ushort hv = (ushort)((hiw >> sh) & 0xFFFFu);
            ushort lv = (ushort)((low >> sh) & 0xFFFFu);
            ah[j] = ok ? (short)hv : (short)0;
            al[j] = ok ? (short)lv : (short)0;
            srcs[j] = meta & 0xFFFFu;
        }
        // B fragment: col = ln31 (feature), same K slots as A -> half-wave-coalesced 64B reads
        short8 bf[NCT];
        #pragma unroll
        for (int j = 0; j < 8; ++j){
            const ushort* hb = hin + (size_t)srcs[j]*IN + ln31;
            #pragma unroll
            for (int ct = 0; ct < NCT; ++ct)
                bf[ct][j] = (short)hb[ct*32];
        }
        #pragma unroll
        for (int ct = 0; ct < NCT; ++ct){
            accH[ct] = __builtin_amdgcn_mfma_f32_32x32x16_bf16(ah, bf[ct], accH[ct], 0, 0, 0);
            accH[ct] = __builtin_amdgcn_mfma_f32_32x32x16_bf16(al, bf[ct], accH[ct], 0, 0, 0);
        }
    }

    // deposit S rows (D layout: col=lane&31, row=(reg&3)+8*(reg>>2)+4*(lane>>5)) + root row
    {
        float ic = invc[d];
        #pragma unroll
        for (int reg = 0; reg < 16; ++reg){
            int row = (reg & 3) + 8*(reg >> 2) + 4*kg2;
            if (row < 25){
                #pragma unroll
                for (int ct = 0; ct < NCT; ++ct)
                    Sb[w*SW + row*IN + ct*32 + ln31] = f2bf(accH[ct][reg]*ic);
            }
        }
        if (IN == 64) Sb[w*SW + 25*64 + lane] = hin[(size_t)d*64 + lane];
        else if (lane < 32) Sb[w*SW + 25*32 + lane] = hin[(size_t)d*32 + lane];
    }
    __syncthreads();

    // ---- node-GEMM: 8 waves = 4 col-tiles x 2 K-halves, M=16 (8 real nodes) ----
    {
        int ct = w & 3, kh = w >> 2;
        int c15 = lane & 15, kg = lane >> 4;
        int nodeg = c15 & 7;
        int cg = kg*8;
        f32x4 a4 = {0.f,0.f,0.f,0.f};
        const ushort* ab = Sb + nodeg*SW + cg;
        const ushort* bb = Bp + ct*512 + (size_t)lane*8;
        #pragma unroll
        for (int k = 0; k < KH; ++k){
            int kt = kh*KH + k;
            short8 a = *(const short8*)(ab + kt*32);
            short8 b = *(const short8*)(bb + (size_t)kt*2048);
            a4 = __builtin_amdgcn_mfma_f32_16x16x32_bf16(a, b, a4, 0, 0, 0);
        }
        if (kh == 1){
            float* rr = red + (ct*64 + lane)*4;
            rr[0]=a4[0]; rr[1]=a4[1]; rr[2]=a4[2]; rr[3]=a4[3];
        }
        __syncthreads();
        if (kh == 0){
            const float* rr = red + (ct*64 + lane)*4;
            int col = ct*16 + c15;
            float bs = bias[col];
            #pragma unroll
            for (int jq = 0; jq < 4; ++jq){
                int r8 = kg*4 + jq;
                if (r8 < 8){
                    float v = a4[jq] + rr[jq] + bs;
                    v = v > 0.f ? v : expm1f(v);
                    if (MODE == 0) ((ushort*)outS)[r8*64 + col] = f2bf(v);
                    else           outS[r8*64 + col] = v;
                }
            }
        }
    }
    __syncthreads();

    // ---- output ----
    if (MODE == 0){
        uint* dst = (uint*)(hout + (size_t)d0*64);
        const uint* srcp = (const uint*)outS;
        for (int i = tid; i < 256; i += 512) dst[i] = srcp[i];
    } else {
        if (w == 0){
            int c = lane;
            float run = 0.f; int gprev = batch[d0];
            for (int r = 0; r < 8; ++r){
                int g = batch[d0 + r];
                if (g != gprev){ atomicAdd(&pooled[gprev*64 + c], run); run = 0.f; gprev = g; }
                run += outS[r*64 + c];
            }
            atomicAdd(&pooled[gprev*64 + c], run);
        } else if (w == 1 && lane == 0){
            int cnt = 0; int gprev = batch[d0];
            for (int r = 0; r < 8; ++r){
                int g = batch[d0 + r];
                if (g != gprev){ atomicAdd(&gcnt[gprev], cnt); cnt = 0; gprev = g; }
                cnt++;
            }
            atomicAdd(&gcnt[gprev], cnt);
        }
    }
}

// ---------------- head: graph mean-pool -> fc -> log_softmax ----------------
__global__ __launch_bounds__(128) void head_k(const float* __restrict__ pooled, const int* __restrict__ gcnt,
                                              const float* __restrict__ fcw, const float* __restrict__ fcb,
                                              float* __restrict__ out){
    int g = threadIdx.x;
    if (g >= NG) return;
    float inv = 1.0f / fmaxf((float)gcnt[g], 1.0f);
    float logits[10];
    #pragma unroll
    for (int c = 0; c < 10; ++c) logits[c] = fcb[c];
    for (int o = 0; o < 64; ++o){
        float m = pooled[g*64 + o] * inv;
        #pragma unroll
        for (int c = 0; c < 10; ++c) logits[c] += m * fcw[o*10 + c];
    }
    float mx = logits[0];
    #pragma unroll
    for (int c = 1; c < 10; ++c) mx = fmaxf(mx, logits[c]);
    float ssum = 0.f;
    #pragma unroll
    for (int c = 0; c < 10; ++c) ssum += expf(logits[c] - mx);
    float lse = logf(ssum) + mx;
    #pragma unroll
    for (int c = 0; c < 10; ++c) out[g*10 + c] = logits[c] - lse;
}

extern "C" void kernel_launch(void* const* d_in, const int* in_sizes, int n_in,
                              void* d_out, int out_size, void* d_ws, size_t ws_size,
                              hipStream_t stream) {
    const float* x      = (const float*)d_in[0];
    const float* pseudo = (const float*)d_in[2];
    const int*   ei     = (const int*)  d_in[3];
    const int*   batch  = (const int*)  d_in[4];
    const float* W1     = (const float*)d_in[5];
    const float* root1  = (const float*)d_in[6];
    const float* b1     = (const float*)d_in[7];
    const float* W2     = (const float*)d_in[8];
    const float* root2  = (const float*)d_in[9];
    const float* b2     = (const float*)d_in[10];
    const float* W3     = (const float*)d_in[11];
    const float* root3  = (const float*)d_in[12];
    const float* b3     = (const float*)d_in[13];
    const float* fcw    = (const float*)d_in[14];
    const float* fcb    = (const float*)d_in[15];
    float* out = (float*)d_out;

    char* ws = (char*)d_ws;
    size_t off = 0;
    auto alloc = [&](size_t bytes)->char*{ char* p = ws + off; off += (bytes + 255) / 256 * 256; return p; };
    uint4*  payload2= (uint4*)alloc((size_t)PADCAP*32);
    ushort* h1bf   = (ushort*)alloc((size_t)NN*32*2);
    ushort* h2bf   = (ushort*)alloc((size_t)NN*64*2);
    int*    hist   = (int*)   alloc((size_t)NN*4);
    int*    offsP  = (int*)   alloc((size_t)(NN+1)*4);
    int*    cursor = (int*)   alloc((size_t)NN*4);
    float*  invc   = (float*) alloc((size_t)NN*4);
    int*    bsum   = (int*)   alloc((size_t)NB_SCAN*4);
    int*    bpre   = (int*)   alloc((size_t)NB_SCAN*4);
    ushort* Bp2    = (ushort*)alloc((size_t)26*2048*2);
    ushort* Bp3    = (ushort*)alloc((size_t)52*2048*2);
    float*  pooled = (float*) alloc((size_t)NG*64*4);
    int*    gcnt   = (int*)   alloc((size_t)NG*4);
    (void)ws_size; (void)in_sizes; (void)n_in; (void)out_size;

    zero_k   <<<NB_SCAN, 256, 0, stream>>>(hist, pooled, gcnt);
    hist_k   <<<(NE+255)/256, 256, 0, stream>>>(ei, hist);
    scan1p   <<<NB_SCAN, 256, 0, stream>>>(hist, bsum);
    scan2p   <<<1, 256, 0, stream>>>(bsum, bpre);
    scan3p   <<<NB_SCAN, 256, 0, stream>>>(hist, bpre, offsP, cursor, invc);
    padfill  <<<(NN*16+255)/256, 256, 0, stream>>>(hist, offsP, payload2);
    scatter_k<<<(NE+255)/256, 256, 0, stream>>>(ei, pseudo, cursor, payload2);
    wprep_k<32><<<(26*32*64 + 255)/256, 256, 0, stream>>>(W2, root2, Bp2);
    wprep_k<64><<<(26*64*64 + 255)/256, 256, 0, stream>>>(W3, root3, Bp3);
    reduce1_k<<<NN/4, 256, 0, stream>>>(x, payload2, offsP, hist, invc, W1, root1, b1, h1bf);
    fused_mf2<32,0><<<NN/8, 512, 0, stream>>>(h1bf, payload2, offsP, invc, Bp2, b2, batch, h2bf, pooled, gcnt);
    fused_mf2<64,1><<<NN/8, 512, 0, stream>>>(h2bf, payload2, offsP, invc, Bp3, b3, batch, h2bf, pooled, gcnt);
    head_k   <<<1, 128, 0, stream>>>(pooled, gcnt, fcw, fcb, out);
}

// Round 11
// 330.311 us; speedup vs baseline: 5.4866x; 1.1051x over previous
//
#include <hip/hip_runtime.h>

#define NN 50000
#define NE 800000
#define NG 128
#define NB_SCAN 196        // ceil(NN/256)

typedef unsigned int uint;
typedef unsigned short ushort;
typedef __attribute__((ext_vector_type(8))) short short8;
typedef __attribute__((ext_vector_type(4))) float f32x4;
typedef __attribute__((ext_vector_type(16))) float f32x16;

__device__ __forceinline__ float bf2f(ushort u){ union{uint i; float f;} v; v.i=(uint)u<<16; return v.f; }
__device__ __forceinline__ ushort f2bf(float f){ union{float f; uint i;} v; v.f=f; return (ushort)((v.i + 0x7FFFu + ((v.i>>16)&1u))>>16); }

// ---------------- zero scratch re-initialized every call ----------------
__global__ void zero_k(int* hist, float* pooled, int* gcnt){
    int i = blockIdx.x*blockDim.x + threadIdx.x;
    if (i < NN) hist[i] = 0;
    if (i < NG*64) pooled[i] = 0.f;
    if (i < NG) gcnt[i] = 0;
}

// ---------------- dst histogram ----------------
__global__ void hist_k(const int* __restrict__ ei, int* __restrict__ hist){
    int e = blockIdx.x*blockDim.x + threadIdx.x;
    if (e < NE) atomicAdd(&hist[ei[NE + e]], 1);
}

// ---------------- hierarchical exclusive scan (no padding) ----------------
__global__ __launch_bounds__(256) void scan1(const int* __restrict__ hist, int* __restrict__ bsum){
    __shared__ int sm[256];
    int t = threadIdx.x, i = blockIdx.x*256 + t;
    sm[t] = (i < NN) ? hist[i] : 0;
    __syncthreads();
    for (int o = 128; o > 0; o >>= 1){ if (t < o) sm[t] += sm[t+o]; __syncthreads(); }
    if (t == 0) bsum[blockIdx.x] = sm[0];
}
__global__ __launch_bounds__(256) void scan2(const int* __restrict__ bsum, int* __restrict__ bpre){
    __shared__ int sm[256];
    int t = threadIdx.x;
    int v = (t < NB_SCAN) ? bsum[t] : 0;
    sm[t] = v; __syncthreads();
    int acc = v;
    for (int o = 1; o < 256; o <<= 1){
        int u = (t >= o) ? sm[t-o] : 0; __syncthreads();
        acc += u; sm[t] = acc; __syncthreads();
    }
    if (t < NB_SCAN) bpre[t] = acc - v;
}
__global__ __launch_bounds__(256) void scan3(const int* __restrict__ hist, const int* __restrict__ bpre,
                                             int* __restrict__ offs, int* __restrict__ cursor,
                                             float* __restrict__ invc){
    __shared__ int sm[256];
    int t = threadIdx.x, b = blockIdx.x, i = b*256 + t;
    int v = (i < NN) ? hist[i] : 0;
    sm[t] = v; __syncthreads();
    int acc = v;
    for (int o = 1; o < 256; o <<= 1){
        int u = (t >= o) ? sm[t-o] : 0; __syncthreads();
        acc += u; sm[t] = acc; __syncthreads();
    }
    int excl = acc - v + bpre[b];
    if (i < NN){ offs[i] = excl; cursor[i] = excl; invc[i] = 1.0f/(float)max(v,1); }
    if (i == NN-1) offs[NN] = NE;
}

// ---------------- counting sort: packed bf16 hi/lo corner weights ----------------
// payload2[pos*2]   = {meta, hi01(w00|w10), hi23(w01|w11), lo01}
// payload2[pos*2+1] = {lo23, 0, 0, 0}
__global__ void scatter_k(const int* __restrict__ ei, const float* __restrict__ pseudo,
                          int* __restrict__ cursor, uint4* __restrict__ payload2){
    int e = blockIdx.x*blockDim.x + threadIdx.x;
    if (e >= NE) return;
    float2 ps = *(const float2*)(pseudo + 2*(size_t)e);
    float px = ps.x * 4.0f, py = ps.y * 4.0f;
    int lx = min(max((int)floorf(px), 0), 3);
    int ly = min(max((int)floorf(py), 0), 3);
    float fx = px - (float)lx, fy = py - (float)ly;
    float gx = 1.f - fx, gy = 1.f - fy;
    float w00 = gx*gy, w10 = fx*gy, w01 = gx*fy, w11 = fx*fy;
    ushort h00 = f2bf(w00), h10 = f2bf(w10), h01 = f2bf(w01), h11 = f2bf(w11);
    ushort L00 = f2bf(w00 - bf2f(h00)), L10 = f2bf(w10 - bf2f(h10));
    ushort L01 = f2bf(w01 - bf2f(h01)), L11 = f2bf(w11 - bf2f(h11));
    uint meta = (uint)ei[e] | ((uint)lx<<16) | ((uint)ly<<18);   // src < 65536
    int pos = atomicAdd(&cursor[ei[NE + e]], 1);
    payload2[(size_t)pos*2]   = make_uint4(meta, (uint)h00 | ((uint)h10<<16),
                                                 (uint)h01 | ((uint)h11<<16),
                                                 (uint)L00 | ((uint)L10<<16));
    payload2[(size_t)pos*2+1] = make_uint4((uint)L01 | ((uint)L11<<16), 0u, 0u, 0u);
}

// ---------------- pack [Wflat;root] into MFMA B-fragment layout, bf16 ----------------
// Bp[(kt*4+ct)*512 + lane*8 + j] = Bmat[kt*32 + (lane>>4)*8 + j][ct*16 + (lane&15)]
template<int IN>
__global__ void wprep_k(const float* __restrict__ W, const float* __restrict__ root, ushort* __restrict__ Bp){
    const int total = 26*IN*64;
    int tid = blockIdx.x*blockDim.x + threadIdx.x;
    if (tid >= total) return;
    int j    = tid & 7;
    int lane = (tid >> 3) & 63;
    int ctkt = tid >> 9;
    int ct   = ctkt & 3;
    int kt   = ctkt >> 2;
    int kk   = kt*32 + (lane>>4)*8 + j;
    int col  = ct*16 + (lane & 15);
    float v;
    if (kk < 25*IN){ int k = kk / IN; int i = kk % IN; v = W[((size_t)k*IN + i)*64 + col]; }
    else           { v = root[(size_t)(kk - 25*IN)*64 + col]; }
    Bp[tid] = f2bf(v);
}

// ---------------- layer 1: CSR reduce with tiny W1 in LDS (in=1, out=32) ----------------
__global__ __launch_bounds__(256) void reduce1_k(const float* __restrict__ x, const uint4* __restrict__ payload2,
                                                 const int* __restrict__ offs, const float* __restrict__ invc,
                                                 const float* __restrict__ W1, const float* __restrict__ root1,
                                                 const float* __restrict__ b1, ushort* __restrict__ h1bf){
    __shared__ float w1s[25*32];
    for (int i = threadIdx.x; i < 25*32; i += 256) w1s[i] = W1[i];
    __syncthreads();
    int wid  = threadIdx.x >> 6;
    int lane = threadIdx.x & 63;
    int o    = lane & 31;
    int half = lane >> 5;
    int d    = blockIdx.x*4 + wid;
    int s = offs[d], e = offs[d+1];
    float acc = 0.f;
    for (int p = s; p < e; ++p){
        uint4 q0 = payload2[(size_t)p*2];
        uint lo23 = payload2[(size_t)p*2+1].x;
        uint meta = q0.x;
        int lx = (meta>>16)&3, ly = (meta>>18)&3;
        float wa, wb;
        if (half == 0){ wa = bf2f((ushort)q0.y) + bf2f((ushort)q0.w);
                        wb = bf2f((ushort)q0.z) + bf2f((ushort)lo23); }
        else          { wa = bf2f((ushort)(q0.y>>16)) + bf2f((ushort)(q0.w>>16));
                        wb = bf2f((ushort)(q0.z>>16)) + bf2f((ushort)(lo23>>16)); }
        float xs = x[meta & 0xFFFF];
        int ka = ly*5 + lx + half;
        acc += (wa*w1s[ka*32 + o] + wb*w1s[(ka+5)*32 + o]) * xs;
    }
    acc += __shfl_xor(acc, 32);
    if (half == 0){
        float val = acc*invc[d] + x[d]*root1[o] + b1[o];
        val = val > 0.f ? val : expm1f(val);
        h1bf[(size_t)d*32 + o] = f2bf(val);
    }
}

// ---------------- fused layer: 32x32x16 edge-GEMM + 16x16x32 node-GEMM, 16 nodes/block ----------------
// 512 threads = 8 waves; each wave runs 2 nodes sequentially in the edge phase.
// Sb stored in node-GEMM FRAGMENT layout [kt][lane64][8] -> conflict-free b128 A-reads.
// No padding: K-step tail zero-filled during LDS staging.
template<int IN, int MODE>
__global__ __launch_bounds__(512) void fused_mf3(
        const ushort* __restrict__ hin, const uint4* __restrict__ payload2,
        const int* __restrict__ offs, const float* __restrict__ invc,
        const ushort* __restrict__ Bp, const float* __restrict__ bias,
        const int* __restrict__ batch, ushort* __restrict__ hout,
        float* __restrict__ pooled, int* __restrict__ gcnt)
{
    constexpr int NCT = IN/32;            // feature col-tiles of 32
    constexpr int KT  = 26*IN/32, KH = KT/2;
    __shared__ __align__(16) ushort Sb[KT*512];
    __shared__ __align__(16) uint4 estage[8][32];
    __shared__ float red[1024];
    __shared__ float outS[1024];

    const int tid = threadIdx.x, lane = tid & 63, w = tid >> 6;
    const int ln31 = lane & 31, kg2 = lane >> 5;
    const int d0 = blockIdx.x * 16;
    const int i0 = ln31 % 5, j0 = ln31 / 5;
    const bool rv = (ln31 < 25);

    for (int nn = 0; nn < 2; ++nn){
        const int node = w*2 + nn;
        const int d = d0 + node;
        int s = offs[d];
        int h = offs[d+1] - s;
        int steps = (h + 15) >> 4;

        f32x16 accH[NCT];
        #pragma unroll
        for (int ct = 0; ct < NCT; ++ct)
            #pragma unroll
            for (int q = 0; q < 16; ++q) accH[ct][q] = 0.f;

        for (int ks = 0; ks < steps; ++ks){
            int rem2 = (h - ks*16)*2;         // valid uint4 slots this step (cap 32)
            if (lane < 32){
                uint4 v = make_uint4(0u,0u,0u,0u);
                if (lane < rem2) v = payload2[(size_t)(s + ks*16)*2 + lane];
                estage[w][lane] = v;
            }
            short8 ah, al;
            uint srcs[8];
            #pragma unroll
            for (int j = 0; j < 8; ++j){
                int es = kg2*8 + j;
                uint4 q0  = estage[w][es*2];
                uint lo23 = estage[w][es*2+1].x;
                uint meta = q0.x;
                int lx = (meta>>16)&3, ly = (meta>>18)&3;
                int dx = i0 - lx, dy = j0 - ly;
                bool ok = rv && ((uint)dx < 2u) && ((uint)dy < 2u);
                uint hiw = (dy == 1) ? q0.z : q0.y;
                uint low = (dy == 1) ? lo23 : q0.w;
                int sh = (dx & 1) << 4;
                ah[j] = ok ? (short)((hiw >> sh) & 0xFFFFu) : (short)0;
                al[j] = ok ? (short)((low >> sh) & 0xFFFFu) : (short)0;
                srcs[j] = meta & 0xFFFFu;
            }
            short8 bfv[NCT];
            #pragma unroll
            for (int j = 0; j < 8; ++j){
                const ushort* hb = hin + (size_t)srcs[j]*IN + ln31;
                #pragma unroll
                for (int ct = 0; ct < NCT; ++ct)
                    bfv[ct][j] = (short)hb[ct*32];
            }
            #pragma unroll
            for (int ct = 0; ct < NCT; ++ct){
                accH[ct] = __builtin_amdgcn_mfma_f32_32x32x16_bf16(ah, bfv[ct], accH[ct], 0, 0, 0);
                accH[ct] = __builtin_amdgcn_mfma_f32_32x32x16_bf16(al, bfv[ct], accH[ct], 0, 0, 0);
            }
        }

        // deposit into fragment layout: k = r*IN + f -> Sb[(k>>5)*512 + ((k>>3)&3)*128 + node*8 + (k&7)]
        {
            float ic = invc[d];
            int jd  = ln31 & 7;
            int l3  = ln31 >> 3;
            #pragma unroll
            for (int reg = 0; reg < 16; ++reg){
                int r = (reg & 3) + 8*(reg >> 2) + 4*kg2;
                if (r < 25){
                    #pragma unroll
                    for (int ct = 0; ct < NCT; ++ct){
                        int kt  = r*NCT + ct;
                        int kgt = (ct*4 + l3) & 3;
                        Sb[kt*512 + kgt*128 + node*8 + jd] = f2bf(accH[ct][reg]*ic);
                    }
                }
            }
            // root row r = 25: value h[d][f]
            if (IN == 64){
                int f = lane;
                Sb[(25*NCT + (f>>5))*512 + ((f>>3)&3)*128 + node*8 + (f&7)] = hin[(size_t)d*64 + f];
            } else if (lane < 32){
                int f = lane;
                Sb[25*512 + ((f>>3)&3)*128 + node*8 + (f&7)] = hin[(size_t)d*32 + f];
            }
        }
    }
    __syncthreads();

    // ---- node-GEMM: 8 waves = 4 col-tiles x 2 K-halves, M=16 (16 nodes, all valid) ----
    {
        int ct = w & 3, kh = w >> 2;
        int c15 = lane & 15, kg = lane >> 4;
        f32x4 a4 = {0.f,0.f,0.f,0.f};
        const ushort* bb = Bp + ct*512 + (size_t)lane*8;
        #pragma unroll
        for (int k = 0; k < KH; ++k){
            int kt = kh*KH + k;
            short8 a = *(const short8*)(Sb + kt*512 + lane*8);
            short8 b = *(const short8*)(bb + (size_t)kt*2048);
            a4 = __builtin_amdgcn_mfma_f32_16x16x32_bf16(a, b, a4, 0, 0, 0);
        }
        if (kh == 1){
            float* rr = red + (ct*64 + lane)*4;
            rr[0]=a4[0]; rr[1]=a4[1]; rr[2]=a4[2]; rr[3]=a4[3];
        }
        __syncthreads();
        if (kh == 0){
            const float* rr = red + (ct*64 + lane)*4;
            int col = ct*16 + c15;
            float bs = bias[col];
            #pragma unroll
            for (int jq = 0; jq < 4; ++jq){
                int r16 = kg*4 + jq;
                float v = a4[jq] + rr[jq] + bs;
                v = v > 0.f ? v : expm1f(v);
                if (MODE == 0) ((ushort*)outS)[r16*64 + col] = f2bf(v);
                else           outS[r16*64 + col] = v;
            }
        }
    }
    __syncthreads();

    // ---- output ----
    if (MODE == 0){
        uint* dst = (uint*)(hout + (size_t)d0*64);
        const uint* srcp = (const uint*)outS;
        dst[tid] = srcp[tid];                 // 16*64 bf16 = 512 uints
    } else {
        if (w == 0){
            int c = lane;
            float run = 0.f; int gprev = batch[d0];
            for (int r = 0; r < 16; ++r){
                int g = batch[d0 + r];
                if (g != gprev){ atomicAdd(&pooled[gprev*64 + c], run); run = 0.f; gprev = g; }
                run += outS[r*64 + c];
            }
            atomicAdd(&pooled[gprev*64 + c], run);
        } else if (w == 1 && lane == 0){
            int cnt = 0; int gprev = batch[d0];
            for (int r = 0; r < 16; ++r){
                int g = batch[d0 + r];
                if (g != gprev){ atomicAdd(&gcnt[gprev], cnt); cnt = 0; gprev = g; }
                cnt++;
            }
            atomicAdd(&gcnt[gprev], cnt);
        }
    }
}

// ---------------- head: graph mean-pool -> fc -> log_softmax ----------------
__global__ __launch_bounds__(128) void head_k(const float* __restrict__ pooled, const int* __restrict__ gcnt,
                                              const float* __restrict__ fcw, const float* __restrict__ fcb,
                                              float* __restrict__ out){
    int g = threadIdx.x;
    if (g >= NG) return;
    float inv = 1.0f / fmaxf((float)gcnt[g], 1.0f);
    float logits[10];
    #pragma unroll
    for (int c = 0; c < 10; ++c) logits[c] = fcb[c];
    for (int o = 0; o < 64; ++o){
        float m = pooled[g*64 + o] * inv;
        #pragma unroll
        for (int c = 0; c < 10; ++c) logits[c] += m * fcw[o*10 + c];
    }
    float mx = logits[0];
    #pragma unroll
    for (int c = 1; c < 10; ++c) mx = fmaxf(mx, logits[c]);
    float ssum = 0.f;
    #pragma unroll
    for (int c = 0; c < 10; ++c) ssum += expf(logits[c] - mx);
    float lse = logf(ssum) + mx;
    #pragma unroll
    for (int c = 0; c < 10; ++c) out[g*10 + c] = logits[c] - lse;
}

extern "C" void kernel_launch(void* const* d_in, const int* in_sizes, int n_in,
                              void* d_out, int out_size, void* d_ws, size_t ws_size,
                              hipStream_t stream) {
    const float* x      = (const float*)d_in[0];
    const float* pseudo = (const float*)d_in[2];
    const int*   ei     = (const int*)  d_in[3];
    const int*   batch  = (const int*)  d_in[4];
    const float* W1     = (const float*)d_in[5];
    const float* root1  = (const float*)d_in[6];
    const float* b1     = (const float*)d_in[7];
    const float* W2     = (const float*)d_in[8];
    const float* root2  = (const float*)d_in[9];
    const float* b2     = (const float*)d_in[10];
    const float* W3     = (const float*)d_in[11];
    const float* root3  = (const float*)d_in[12];
    const float* b3     = (const float*)d_in[13];
    const float* fcw    = (const float*)d_in[14];
    const float* fcb    = (const float*)d_in[15];
    float* out = (float*)d_out;

    char* ws = (char*)d_ws;
    size_t off = 0;
    auto alloc = [&](size_t bytes)->char*{ char* p = ws + off; off += (bytes + 255) / 256 * 256; return p; };
    uint4*  payload2= (uint4*)alloc((size_t)NE*32);
    ushort* h1bf   = (ushort*)alloc((size_t)NN*32*2);
    ushort* h2bf   = (ushort*)alloc((size_t)NN*64*2);
    int*    hist   = (int*)   alloc((size_t)NN*4);
    int*    offs   = (int*)   alloc((size_t)(NN+1)*4);
    int*    cursor = (int*)   alloc((size_t)NN*4);
    float*  invc   = (float*) alloc((size_t)NN*4);
    int*    bsum   = (int*)   alloc((size_t)NB_SCAN*4);
    int*    bpre   = (int*)   alloc((size_t)NB_SCAN*4);
    ushort* Bp2    = (ushort*)alloc((size_t)26*2048*2);
    ushort* Bp3    = (ushort*)alloc((size_t)52*2048*2);
    float*  pooled = (float*) alloc((size_t)NG*64*4);
    int*    gcnt   = (int*)   alloc((size_t)NG*4);
    (void)ws_size; (void)in_sizes; (void)n_in; (void)out_size;

    zero_k   <<<NB_SCAN, 256, 0, stream>>>(hist, pooled, gcnt);
    hist_k   <<<(NE+255)/256, 256, 0, stream>>>(ei, hist);
    scan1    <<<NB_SCAN, 256, 0, stream>>>(hist, bsum);
    scan2    <<<1, 256, 0, stream>>>(bsum, bpre);
    scan3    <<<NB_SCAN, 256, 0, stream>>>(hist, bpre, offs, cursor, invc);
    scatter_k<<<(NE+255)/256, 256, 0, stream>>>(ei, pseudo, cursor, payload2);
    wprep_k<32><<<(26*32*64 + 255)/256, 256, 0, stream>>>(W2, root2, Bp2);
    wprep_k<64><<<(26*64*64 + 255)/256, 256, 0, stream>>>(W3, root3, Bp3);
    reduce1_k<<<NN/4, 256, 0, stream>>>(x, payload2, offs, invc, W1, root1, b1, h1bf);
    fused_mf3<32,0><<<NN/16, 512, 0, stream>>>(h1bf, payload2, offs, invc, Bp2, b2, batch, h2bf, pooled, gcnt);
    fused_mf3<64,1><<<NN/16, 512, 0, stream>>>(h2bf, payload2, offs, invc, Bp3, b3, batch, h2bf, pooled, gcnt);
    head_k   <<<1, 128, 0, stream>>>(pooled, gcnt, fcw, fcb, out);
}